// Round 13
// baseline (168.106 us; speedup 1.0000x reference)
//
#include <hip/hip_runtime.h>

#define NN 100000
#define NE 3200000
#define FIN 256
#define H1 8
#define C2 16
#define NEG 0.2f

#define BKT 64                        // dst nodes per fine bucket
#define NB 1563                       // fine buckets with real nodes
#define NBP 1568                      // padded fine buckets (32 supers * 49)
#define CAP 2560                      // max edges per fine bucket (mean 2048)
#define SB 32                         // super-buckets
#define SBN 3136                      // nodes per super (49 * 64)
#define FPS 49                        // fine buckets per super
#define SCAP 110000                   // super region capacity (mean 100352)
#define P1B 1024                      // partition-1 blocks
#define EPB1 3125                     // NE / P1B
#define LINB 1563                     // lin logical blocks (64 nodes each)
#define P2CAP 3520                    // >= max super slice
#define XR 132                        // x-tile row stride

// ---- tiny clear kernel ----
__global__ __launch_bounds__(512) void k_clr(int* __restrict__ g) {
    int i = blockIdx.x * 512 + threadIdx.x;
    if (i < SB + NBP) g[i] = 0;
}

// ---- partition stage 1 (standalone, high occupancy) ----
__global__ __launch_bounds__(512) void k_p1s(const int* __restrict__ ei,
                                             int* __restrict__ gcur1,
                                             int* __restrict__ sup1) {
    __shared__ int buf[EPB1];
    __shared__ int cnt[SB], nb[SB], cnt2[SB], gb[SB];
    int tid = threadIdx.x;
    int base = blockIdx.x * EPB1;
    if (tid < SB) { cnt[tid] = 0; cnt2[tid] = 0; }
    int es[7], ed[7];
    #pragma unroll
    for (int r = 0; r < 7; ++r) {
        int i = tid + r * 512;
        if (i < EPB1) { es[r] = ei[base + i]; ed[r] = ei[NE + base + i]; }
    }
    __syncthreads();
    #pragma unroll
    for (int r = 0; r < 7; ++r) {
        int i = tid + r * 512;
        if (i < EPB1) atomicAdd(&cnt[ed[r] / SBN], 1);
    }
    __syncthreads();
    if (tid < SB) {                    // scan + global reserve
        int v = cnt[tid], inc = v;
        #pragma unroll
        for (int off = 1; off < SB; off <<= 1) {
            int u = __shfl_up(inc, off, 64);
            if (tid >= off) inc += u;
        }
        nb[tid] = inc - v;
        gb[tid] = atomicAdd(&gcur1[tid], v);
    }
    __syncthreads();
    #pragma unroll
    for (int r = 0; r < 7; ++r) {
        int i = tid + r * 512;
        if (i < EPB1) {
            int s = ed[r] / SBN;
            int rr = ed[r] - s * SBN;
            int k = atomicAdd(&cnt2[s], 1);
            buf[nb[s] + k] = (rr << 17) | es[r];
        }
    }
    __syncthreads();
    for (int s = 0; s < SB; ++s) {     // coalesced run flush
        int c = cnt[s], b = gb[s], o = nb[s];
        size_t dbase = (size_t)s * SCAP + b;
        for (int i = tid; i < c; i += 512)
            if (b + i < SCAP) sup1[dbase + i] = buf[o + i];
    }
}

// ---- fused: role by blockIdx%5 (3 lin : 2 p2) ----
__global__ __launch_bounds__(512) void k_c(
        const float* __restrict__ x,
        const float* __restrict__ Wl, const float* __restrict__ bl,
        const float* __restrict__ Wr, const float* __restrict__ br,
        float* __restrict__ xl1, float* __restrict__ xr1,
        const int* __restrict__ sup1, const int* __restrict__ gcur1,
        int* __restrict__ gcur2, int* __restrict__ bedges) {
    __shared__ int smem[10240];        // 40 KB shared by both roles
    int tid = threadIdx.x;
    int m = blockIdx.x % 5, d = blockIdx.x / 5;

    if (m >= 3) {
        // ---------------- partition stage 2 ----------------
        int idx = d * 2 + (m - 3);
        if (idx >= P1B) return;        // 1024 p2 blocks
        int* buf  = smem;              // P2CAP
        int* cnt  = smem + P2CAP;
        int* nb   = cnt + FPS;
        int* cnt2 = nb + FPS;
        int* gb   = cnt2 + FPS;
        int s   = idx >> 5;
        int sub = idx & 31;
        int total = gcur1[s]; if (total > SCAP) total = SCAP;
        int beg = (int)((long)total * sub / 32);
        int end = (int)((long)total * (sub + 1) / 32);
        int n = end - beg;
        const int* sp = sup1 + (size_t)s * SCAP + beg;
        if (tid < FPS) { cnt[tid] = 0; cnt2[tid] = 0; }
        int pk[7];
        #pragma unroll
        for (int r = 0; r < 7; ++r) {
            int i = tid + r * 512;
            if (i < n) pk[r] = sp[i];
        }
        __syncthreads();
        #pragma unroll
        for (int r = 0; r < 7; ++r) {
            int i = tid + r * 512;
            if (i < n) atomicAdd(&cnt[(pk[r] >> 17) >> 6], 1);
        }
        __syncthreads();
        if (tid < 64) {
            int v = (tid < FPS) ? cnt[tid] : 0, inc = v;
            #pragma unroll
            for (int off = 1; off < 64; off <<= 1) {
                int u = __shfl_up(inc, off, 64);
                if (tid >= off) inc += u;
            }
            if (tid < FPS) {
                nb[tid] = inc - v;
                gb[tid] = atomicAdd(&gcur2[s * FPS + tid], v);
            }
        }
        __syncthreads();
        #pragma unroll
        for (int r = 0; r < 7; ++r) {
            int i = tid + r * 512;
            if (i < n) {
                int fb = (pk[r] >> 17) >> 6;
                int k = atomicAdd(&cnt2[fb], 1);
                buf[nb[fb] + k] = (((pk[r] >> 17) & 63) << 17) | (pk[r] & 0x1FFFF);
            }
        }
        __syncthreads();
        for (int fb = 0; fb < FPS; ++fb) {
            int c = cnt[fb], b = gb[fb], o = nb[fb];
            size_t dbase = (size_t)(s * FPS + fb) * CAP + b;
            for (int i = tid; i < c; i += 512)
                if (b + i < CAP) bedges[dbase + i] = buf[o + i];
        }
    } else {
        // ---- layer-1 linear: x tile in LDS (coalesced), weights via s_load
        int lb = d * 3 + m;            // 0..1562
        if (lb >= LINB) return;
        int blkNode = lb * 64;
        float* xf   = (float*)smem;    // [64][XR]
        float* part = (float*)smem;    // reuse: [8][64][20]
        int lane = tid & 63;
        int wq = __builtin_amdgcn_readfirstlane(tid >> 6);   // k-sixteenth 0..7

        float accl[8] = {0,0,0,0,0,0,0,0}, accr[8] = {0,0,0,0,0,0,0,0};

        #pragma unroll
        for (int ph = 0; ph < 2; ++ph) {
            __syncthreads();
            #pragma unroll
            for (int pass = 0; pass < 4; ++pass) {
                int i = tid + pass * 512;      // float4 index, 2048 total
                int row = i >> 5, c4 = i & 31;
                int node = blkNode + row; if (node >= NN) node = NN - 1;
                float4 v = *(const float4*)(x + (size_t)node * FIN + ph * 128 + c4 * 4);
                *(float4*)&xf[row * XR + c4 * 4] = v;
            }
            __syncthreads();
            int kbase = ph * 128 + wq * 16;
            const float* wlp = Wl + kbase * 8;     // scalar (wave-uniform)
            const float* wrp = Wr + kbase * 8;
            const float* xrow = &xf[lane * XR + wq * 16];
            #pragma unroll
            for (int jq = 0; jq < 4; ++jq) {
                float4 xv = *(const float4*)(xrow + jq * 4);
                float xa[4] = {xv.x, xv.y, xv.z, xv.w};
                #pragma unroll
                for (int r = 0; r < 4; ++r) {
                    int k = jq * 4 + r;
                    #pragma unroll
                    for (int h = 0; h < 8; ++h) {
                        accl[h] = fmaf(xa[r], wlp[k * 8 + h], accl[h]);
                        accr[h] = fmaf(xa[r], wrp[k * 8 + h], accr[h]);
                    }
                }
            }
        }
        __syncthreads();
        float* pw = part + (size_t)(wq * 64 + lane) * 20;
        *(float4*)(pw)      = make_float4(accl[0], accl[1], accl[2], accl[3]);
        *(float4*)(pw + 4)  = make_float4(accl[4], accl[5], accl[6], accl[7]);
        *(float4*)(pw + 8)  = make_float4(accr[0], accr[1], accr[2], accr[3]);
        *(float4*)(pw + 12) = make_float4(accr[4], accr[5], accr[6], accr[7]);
        __syncthreads();
        int n2 = tid >> 3, p = tid & 7;
        float s0 = 0.f, s1 = 0.f;
        #pragma unroll
        for (int w2 = 0; w2 < 8; ++w2) {
            const float* pr = part + (size_t)(w2 * 64 + n2) * 20 + p * 2;
            s0 += pr[0]; s1 += pr[1];
        }
        int node = blkNode + n2;
        if (node < NN) {
            int o = p * 2;
            if (o < 8) {
                s0 += bl[o]; s1 += bl[o + 1];
                *(float2*)(xl1 + (size_t)node * H1 + o) = make_float2(s0, s1);
            } else {
                s0 += br[o - 8]; s1 += br[o - 7];
                *(float2*)(xr1 + (size_t)node * H1 + (o - 8)) = make_float2(s0, s1);
            }
        }
    }
}

// ---- fused: per-bucket counting sort + layer-1 GAT (prefetched) + mid GEMM
__global__ __launch_bounds__(512) void k_sortgat1(
        int* __restrict__ bedges, const int* __restrict__ gcur2,
        int* __restrict__ meta,
        const float* __restrict__ xl, const float* __restrict__ xr,
        const float* __restrict__ att, const float* __restrict__ bias,
        const float* __restrict__ Wl2, const float* __restrict__ bl2,
        const float* __restrict__ Wr2, const float* __restrict__ br2,
        float* __restrict__ xl2, float* __restrict__ xr2) {
    __shared__ int sorted[CAP];
    __shared__ int hist[BKT], nbase[BKT], scnt[BKT];
    int bkt = blockIdx.x;
    int tid = threadIdx.x;
    int ecnt = gcur2[bkt]; if (ecnt > CAP) ecnt = CAP;
    int* be = bedges + (size_t)bkt * CAP;
    if (tid < BKT) { hist[tid] = 0; scnt[tid] = 0; }
    __syncthreads();
    for (int i = tid; i < ecnt; i += 512)
        atomicAdd(&hist[be[i] >> 17], 1);
    __syncthreads();
    if (tid < BKT) {                   // wave-parallel exclusive scan
        int v = hist[tid], inc = v;
        #pragma unroll
        for (int off = 1; off < 64; off <<= 1) {
            int u = __shfl_up(inc, off, 64);
            if (tid >= off) inc += u;
        }
        nbase[tid] = inc - v;
        meta[bkt * BKT + tid] = ((inc - v) << 16) | v;   // for layer 2
    }
    __syncthreads();
    for (int i = tid; i < ecnt; i += 512) {
        int pk = be[i];
        int dl = pk >> 17;
        int r = atomicAdd(&scnt[dl], 1);
        sorted[nbase[dl] + r] = pk & 0x1FFFF;
    }
    __syncthreads();
    for (int i = tid; i < ecnt; i += 512)   // writeback for layer 2
        be[i] = sorted[i];

    // -------- layer-1 GAT (D=8), software-prefetched node pipeline --------
    int wave = tid >> 6, lane = tid & 63;
    int q = lane & 1, eo = lane >> 1;       // LPE=2, EPC=32

    float attq[4], biasq[4];
    #pragma unroll
    for (int j = 0; j < 4; ++j) { attq[j] = att[q * 4 + j]; biasq[j] = bias[q * 4 + j]; }
    float wl2c[H1], wr2c[H1], bl2c = 0.f, br2c = 0.f;
    if (lane < C2) {
        #pragma unroll
        for (int d = 0; d < H1; ++d) {
            wl2c[d] = Wl2[d * C2 + lane];
            wr2c[d] = Wr2[d * C2 + lane];
        }
        bl2c = bl2[lane]; br2c = br2[lane];
    }

    // prologue: prefetch first node's state
    int pN = wave;
    int pG = bkt * BKT + pN; int pGc = pG < NN ? pG : NN - 1;
    int pDeg = hist[pN] + 1, pNb = nbase[pN];
    float4 pXr = ((const float4*)(xr + (size_t)pGc * H1))[q];
    int pSrc = (eo > 0 && eo < pDeg) ? sorted[pNb + eo - 1] : pGc;
    float4 pV = ((const float4*)(xl + (size_t)pSrc * H1))[q];

    #pragma unroll 1
    for (int n = wave; n < BKT; n += 8) {
        // rotate current in
        int g = bkt * BKT + n;
        int gc = g < NN ? g : NN - 1;
        int deg = pDeg, nb_ = pNb;
        float4 xr4 = pXr, v0 = pV;

        // prefetch next node
        int n2 = n + 8;
        if (n2 < BKT) {
            int g2 = bkt * BKT + n2; int g2c = g2 < NN ? g2 : NN - 1;
            pDeg = hist[n2] + 1; pNb = nbase[n2];
            pXr = ((const float4*)(xr + (size_t)g2c * H1))[q];
            int s2 = (eo > 0 && eo < pDeg) ? sorted[pNb + eo - 1] : g2c;
            pV = ((const float4*)(xl + (size_t)s2 * H1))[q];
        }

        float xrq[4] = {xr4.x, xr4.y, xr4.z, xr4.w};
        float denom, acc[4];
        {
            float xa[4] = {v0.x, v0.y, v0.z, v0.w};
            float s = 0.f;
            #pragma unroll
            for (int j = 0; j < 4; ++j) {
                float w = xa[j] + xrq[j];
                w = fmaxf(w, NEG * w);
                s = fmaf(attq[j], w, s);
            }
            s += __shfl_xor(s, 1, 64);
            float ex = (eo < deg) ? __expf(s) : 0.f;
            denom = ex;
            #pragma unroll
            for (int j = 0; j < 4; ++j) acc[j] = ex * xa[j];
        }
        if (deg > 32) {                 // chunk 1, wave-uniform guard
            int e = 32 + eo;
            int src = (e < deg) ? sorted[nb_ + e - 1] : gc;
            float4 v = ((const float4*)(xl + (size_t)src * H1))[q];
            float xa[4] = {v.x, v.y, v.z, v.w};
            float s = 0.f;
            #pragma unroll
            for (int j = 0; j < 4; ++j) {
                float w = xa[j] + xrq[j];
                w = fmaxf(w, NEG * w);
                s = fmaf(attq[j], w, s);
            }
            s += __shfl_xor(s, 1, 64);
            float ex = (e < deg) ? __expf(s) : 0.f;
            denom += ex;
            #pragma unroll
            for (int j = 0; j < 4; ++j) acc[j] = fmaf(ex, xa[j], acc[j]);
        }
        for (int e0 = 64; e0 < deg; e0 += 32) {   // rare: deg > 64
            int e = e0 + eo;
            int src = (e < deg) ? sorted[nb_ + e - 1] : gc;
            float4 v = ((const float4*)(xl + (size_t)src * H1))[q];
            float xa[4] = {v.x, v.y, v.z, v.w};
            float s = 0.f;
            #pragma unroll
            for (int j = 0; j < 4; ++j) {
                float w = xa[j] + xrq[j];
                w = fmaxf(w, NEG * w);
                s = fmaf(attq[j], w, s);
            }
            s += __shfl_xor(s, 1, 64);
            float ex = (e < deg) ? __expf(s) : 0.f;
            denom += ex;
            #pragma unroll
            for (int j = 0; j < 4; ++j) acc[j] = fmaf(ex, xa[j], acc[j]);
        }

        #pragma unroll
        for (int off = 2; off < 64; off <<= 1) {
            denom += __shfl_xor(denom, off, 64);
            #pragma unroll
            for (int j = 0; j < 4; ++j)
                acc[j] += __shfl_xor(acc[j], off, 64);
        }
        float inv = 1.f / denom;

        float h[4];
        #pragma unroll
        for (int j = 0; j < 4; ++j)
            h[j] = fmaxf(acc[j] * inv + biasq[j], 0.f);
        float hd[H1];
        #pragma unroll
        for (int d = 0; d < H1; ++d)
            hd[d] = __shfl(h[d & 3], d >> 2, 64);
        if (lane < C2 && g < NN) {
            float al = bl2c, ar = br2c;
            #pragma unroll
            for (int d = 0; d < H1; ++d) {
                al = fmaf(hd[d], wl2c[d], al);
                ar = fmaf(hd[d], wr2c[d], ar);
            }
            xl2[(size_t)g * C2 + lane] = al;
            xr2[(size_t)g * C2 + lane] = ar;
        }
    }
}

// ---- layer-2 GAT gather (D=16): 4 nodes/wave, scalarized meta/addresses ----
__global__ __launch_bounds__(128) void k_gat2L(
        const int* __restrict__ sorted_g, const int* __restrict__ meta,
        const float* __restrict__ xl, const float* __restrict__ xr,
        const float* __restrict__ att, const float* __restrict__ bias,
        float* __restrict__ out) {
    int wv = (blockIdx.x * 128 + threadIdx.x) >> 6;
    int gbase = __builtin_amdgcn_readfirstlane(wv << 2);
    int lane = threadIdx.x & 63;
    int q = lane & 3, eo = lane >> 2;       // LPE=4, EPC=16

    float attq[4], biasq[4];
    #pragma unroll
    for (int j = 0; j < 4; ++j) { attq[j] = att[q * 4 + j]; biasq[j] = bias[q * 4 + j]; }

    #pragma unroll 2
    for (int i = 0; i < 4; ++i) {
        int g = gbase + i;
        int mt = meta[g];                   // s_load (g scalar)
        int deg = (mt & 0xFFFF) + 1;
        const int* sg = sorted_g + (size_t)(g >> 6) * CAP + (mt >> 16);

        float4 xr4 = ((const float4*)(xr + (size_t)g * C2))[q];
        float xrq[4] = {xr4.x, xr4.y, xr4.z, xr4.w};

        float denom = 0.f;
        float acc[4] = {0.f, 0.f, 0.f, 0.f};

        #pragma unroll
        for (int c = 0; c < 4; ++c) {
            if (c == 0 || deg > c * 16) {   // wave-uniform guard
                int e = c * 16 + eo;
                int src = (e > 0 && e < deg) ? sg[e - 1] : g;
                float4 v = ((const float4*)(xl + (size_t)src * C2))[q];
                float xv[4] = {v.x, v.y, v.z, v.w};
                float s = 0.f;
                #pragma unroll
                for (int j = 0; j < 4; ++j) {
                    float w = xv[j] + xrq[j];
                    w = fmaxf(w, NEG * w);
                    s = fmaf(attq[j], w, s);
                }
                s += __shfl_xor(s, 1, 64);
                s += __shfl_xor(s, 2, 64);
                float ex = (e < deg) ? __expf(s) : 0.f;
                denom += ex;
                #pragma unroll
                for (int j = 0; j < 4; ++j)
                    acc[j] = fmaf(ex, xv[j], acc[j]);
            }
        }
        for (int e0 = 64; e0 < deg; e0 += 16) {   // rare: deg > 64
            int e = e0 + eo;
            int src = (e < deg) ? sg[e - 1] : g;
            float4 v = ((const float4*)(xl + (size_t)src * C2))[q];
            float xv[4] = {v.x, v.y, v.z, v.w};
            float s = 0.f;
            #pragma unroll
            for (int j = 0; j < 4; ++j) {
                float w = xv[j] + xrq[j];
                w = fmaxf(w, NEG * w);
                s = fmaf(attq[j], w, s);
            }
            s += __shfl_xor(s, 1, 64);
            s += __shfl_xor(s, 2, 64);
            float ex = (e < deg) ? __expf(s) : 0.f;
            denom += ex;
            #pragma unroll
            for (int j = 0; j < 4; ++j)
                acc[j] = fmaf(ex, xv[j], acc[j]);
        }

        #pragma unroll
        for (int off = 4; off < 64; off <<= 1) {
            denom += __shfl_xor(denom, off, 64);
            #pragma unroll
            for (int j = 0; j < 4; ++j)
                acc[j] += __shfl_xor(acc[j], off, 64);
        }
        float inv = 1.f / denom;

        if (eo == 0) {
            float4 r;
            r.x = acc[0] * inv + biasq[0];
            r.y = acc[1] * inv + biasq[1];
            r.z = acc[2] * inv + biasq[2];
            r.w = acc[3] * inv + biasq[3];
            ((float4*)(out + (size_t)g * C2))[q] = r;
        }
    }
}

extern "C" void kernel_launch(void* const* d_in, const int* in_sizes, int n_in,
                              void* d_out, int out_size, void* d_ws, size_t ws_size,
                              hipStream_t stream) {
    const float* x     = (const float*)d_in[0];
    const int*   ei    = (const int*)d_in[1];
    const float* Wl1   = (const float*)d_in[2];
    const float* bl1   = (const float*)d_in[3];
    const float* Wr1   = (const float*)d_in[4];
    const float* br1   = (const float*)d_in[5];
    const float* att1  = (const float*)d_in[6];
    const float* bias1 = (const float*)d_in[7];
    const float* Wl2   = (const float*)d_in[8];
    const float* bl2   = (const float*)d_in[9];
    const float* Wr2   = (const float*)d_in[10];
    const float* br2   = (const float*)d_in[11];
    const float* att2  = (const float*)d_in[12];
    const float* bias2 = (const float*)d_in[13];
    float* out = (float*)d_out;

    // workspace layout
    int* bedges = (int*)d_ws;                        // NBP*CAP (sorted in-place)
    int* gcur1  = bedges + (size_t)NBP * CAP;        // 32
    int* gcur2  = gcur1 + SB;                        // NBP
    int* meta   = gcur2 + NBP;                       // NBP*64
    float* xl1  = (float*)(meta + NBP * BKT);        // NN*H1
    float* xr1  = xl1 + (size_t)NN * H1;             // NN*H1
    int* sup1   = (int*)(xr1 + (size_t)NN * H1);     // SB*SCAP (14.08 MB)
    float* xl2  = (float*)sup1;                      // overlay: sup1 dead after k_c
    float* xr2  = xl2 + (size_t)NN * C2;             // NN*C2

    k_clr<<<4, 512, 0, stream>>>(gcur1);
    k_p1s<<<P1B, 512, 0, stream>>>(ei, gcur1, sup1);
    k_c<<<2605, 512, 0, stream>>>(x, Wl1, bl1, Wr1, br1, xl1, xr1,
                                  sup1, gcur1, gcur2, bedges);
    k_sortgat1<<<NB, 512, 0, stream>>>(bedges, gcur2, meta, xl1, xr1, att1, bias1,
                                       Wl2, bl2, Wr2, br2, xl2, xr2);
    k_gat2L<<<12500, 128, 0, stream>>>(bedges, meta, xl2, xr2, att2, bias2, out);
}

// Round 14
// 137.924 us; speedup vs baseline: 1.2188x; 1.2188x over previous
//
#include <hip/hip_runtime.h>

#define NN 100000
#define NE 3200000
#define FIN 256
#define H1 8
#define C2 16
#define NEG 0.2f

#define BKT 64                        // dst nodes per fine bucket
#define NB 1563                       // fine buckets with real nodes
#define NBP 1568                      // padded fine buckets (32 supers * 49)
#define CAP 2560                      // max edges per fine bucket (mean 2048)
#define SB 32                         // super-buckets
#define SBN 3136                      // nodes per super (49 * 64)
#define FPS 49                        // fine buckets per super
#define SCAP 110000                   // super region capacity (mean 100352)
#define P1B 1024                      // partition-1 logical blocks
#define EPB1 3125                     // NE / P1B
#define LINB 1563                     // lin logical blocks (64 nodes each)
#define P2CAP 3520                    // >= max super slice
#define XR 132                        // x-tile row stride

// ---- tiny clear kernel ----
__global__ __launch_bounds__(512) void k_clr(int* __restrict__ g) {
    int i = blockIdx.x * 512 + threadIdx.x;
    if (i < SB + NBP) g[i] = 0;
}

// ---- fused front kernel: role by blockIdx%5 (3 lin : 2 p1) ----
__global__ __launch_bounds__(512) void k_b(
        const float* __restrict__ x,
        const float* __restrict__ Wl, const float* __restrict__ bl,
        const float* __restrict__ Wr, const float* __restrict__ br,
        float* __restrict__ xl1, float* __restrict__ xr1,
        const int* __restrict__ ei,
        int* __restrict__ gcur1, int* __restrict__ sup1) {
    __shared__ int smem[10240];        // 40 KB shared by both roles
    int tid = threadIdx.x;
    int m = blockIdx.x % 5, d = blockIdx.x / 5;

    if (m >= 3) {
        // ---------------- partition stage 1 ----------------
        int p1 = d * 2 + (m - 3);
        if (p1 >= P1B) return;
        int* buf  = smem;              // EPB1
        int* cnt  = smem + EPB1;
        int* nb   = cnt + SB;
        int* cnt2 = nb + SB;
        int* gb   = cnt2 + SB;
        int base = p1 * EPB1;
        if (tid < SB) { cnt[tid] = 0; cnt2[tid] = 0; }
        int es[7], ed[7];
        #pragma unroll
        for (int r = 0; r < 7; ++r) {
            int i = tid + r * 512;
            if (i < EPB1) { es[r] = ei[base + i]; ed[r] = ei[NE + base + i]; }
        }
        __syncthreads();
        #pragma unroll
        for (int r = 0; r < 7; ++r) {
            int i = tid + r * 512;
            if (i < EPB1) atomicAdd(&cnt[ed[r] / SBN], 1);
        }
        __syncthreads();
        if (tid < SB) {                // scan + global reserve
            int v = cnt[tid], inc = v;
            #pragma unroll
            for (int off = 1; off < SB; off <<= 1) {
                int u = __shfl_up(inc, off, 64);
                if (tid >= off) inc += u;
            }
            nb[tid] = inc - v;
            gb[tid] = atomicAdd(&gcur1[tid], v);
        }
        __syncthreads();
        #pragma unroll
        for (int r = 0; r < 7; ++r) {
            int i = tid + r * 512;
            if (i < EPB1) {
                int s = ed[r] / SBN;
                int rr = ed[r] - s * SBN;
                int k = atomicAdd(&cnt2[s], 1);
                buf[nb[s] + k] = (rr << 17) | es[r];
            }
        }
        __syncthreads();
        for (int s = 0; s < SB; ++s) { // coalesced run flush
            int c = cnt[s], b = gb[s], o = nb[s];
            size_t dbase = (size_t)s * SCAP + b;
            for (int i = tid; i < c; i += 512)
                if (b + i < SCAP) sup1[dbase + i] = buf[o + i];
        }
    } else {
        // ---- layer-1 linear: x tile in LDS (coalesced), weights via s_load
        int lb = d * 3 + m;            // 0..1562
        if (lb >= LINB) return;
        int blkNode = lb * 64;
        float* xf   = (float*)smem;    // [64][XR]
        float* part = (float*)smem;    // reuse: [8][64][20]
        int lane = tid & 63;
        int wq = __builtin_amdgcn_readfirstlane(tid >> 6);   // k-sixteenth 0..7

        float accl[8] = {0,0,0,0,0,0,0,0}, accr[8] = {0,0,0,0,0,0,0,0};

        #pragma unroll
        for (int ph = 0; ph < 2; ++ph) {
            __syncthreads();
            #pragma unroll
            for (int pass = 0; pass < 4; ++pass) {
                int i = tid + pass * 512;      // float4 index, 2048 total
                int row = i >> 5, c4 = i & 31;
                int node = blkNode + row; if (node >= NN) node = NN - 1;
                float4 v = *(const float4*)(x + (size_t)node * FIN + ph * 128 + c4 * 4);
                *(float4*)&xf[row * XR + c4 * 4] = v;
            }
            __syncthreads();
            int kbase = ph * 128 + wq * 16;
            const float* wlp = Wl + kbase * 8;     // scalar (wave-uniform)
            const float* wrp = Wr + kbase * 8;
            const float* xrow = &xf[lane * XR + wq * 16];
            #pragma unroll
            for (int jq = 0; jq < 4; ++jq) {
                float4 xv = *(const float4*)(xrow + jq * 4);
                float xa[4] = {xv.x, xv.y, xv.z, xv.w};
                #pragma unroll
                for (int r = 0; r < 4; ++r) {
                    int k = jq * 4 + r;
                    #pragma unroll
                    for (int h = 0; h < 8; ++h) {
                        accl[h] = fmaf(xa[r], wlp[k * 8 + h], accl[h]);
                        accr[h] = fmaf(xa[r], wrp[k * 8 + h], accr[h]);
                    }
                }
            }
        }
        __syncthreads();
        float* pw = part + (size_t)(wq * 64 + lane) * 20;
        *(float4*)(pw)      = make_float4(accl[0], accl[1], accl[2], accl[3]);
        *(float4*)(pw + 4)  = make_float4(accl[4], accl[5], accl[6], accl[7]);
        *(float4*)(pw + 8)  = make_float4(accr[0], accr[1], accr[2], accr[3]);
        *(float4*)(pw + 12) = make_float4(accr[4], accr[5], accr[6], accr[7]);
        __syncthreads();
        int n2 = tid >> 3, p = tid & 7;
        float s0 = 0.f, s1 = 0.f;
        #pragma unroll
        for (int w2 = 0; w2 < 8; ++w2) {
            const float* pr = part + (size_t)(w2 * 64 + n2) * 20 + p * 2;
            s0 += pr[0]; s1 += pr[1];
        }
        int node = blkNode + n2;
        if (node < NN) {
            int o = p * 2;
            if (o < 8) {
                s0 += bl[o]; s1 += bl[o + 1];
                *(float2*)(xl1 + (size_t)node * H1 + o) = make_float2(s0, s1);
            } else {
                s0 += br[o - 8]; s1 += br[o - 7];
                *(float2*)(xr1 + (size_t)node * H1 + (o - 8)) = make_float2(s0, s1);
            }
        }
    }
}

// ---- partition stage 2: super slice -> 49 fine buckets (32 slices/super) ---
__global__ __launch_bounds__(512) void k_p2(const int* __restrict__ sup1,
                                            const int* __restrict__ gcur1,
                                            int* __restrict__ gcur2,
                                            int* __restrict__ bedges) {
    __shared__ int buf[P2CAP];
    __shared__ int cnt[FPS], nb[FPS], cnt2[FPS], gb[FPS];
    int s   = blockIdx.x >> 5;
    int sub = blockIdx.x & 31;
    int tid = threadIdx.x;
    int total = gcur1[s]; if (total > SCAP) total = SCAP;
    int beg = (int)((long)total * sub / 32);
    int end = (int)((long)total * (sub + 1) / 32);
    int n = end - beg;
    const int* sp = sup1 + (size_t)s * SCAP + beg;
    if (tid < FPS) { cnt[tid] = 0; cnt2[tid] = 0; }
    int pk[7];
    #pragma unroll
    for (int r = 0; r < 7; ++r) {
        int i = tid + r * 512;
        if (i < n) pk[r] = sp[i];
    }
    __syncthreads();
    #pragma unroll
    for (int r = 0; r < 7; ++r) {
        int i = tid + r * 512;
        if (i < n) atomicAdd(&cnt[(pk[r] >> 17) >> 6], 1);
    }
    __syncthreads();
    if (tid < 64) {
        int v = (tid < FPS) ? cnt[tid] : 0, inc = v;
        #pragma unroll
        for (int off = 1; off < 64; off <<= 1) {
            int u = __shfl_up(inc, off, 64);
            if (tid >= off) inc += u;
        }
        if (tid < FPS) {
            nb[tid] = inc - v;
            gb[tid] = atomicAdd(&gcur2[s * FPS + tid], v);
        }
    }
    __syncthreads();
    #pragma unroll
    for (int r = 0; r < 7; ++r) {
        int i = tid + r * 512;
        if (i < n) {
            int fb = (pk[r] >> 17) >> 6;
            int k = atomicAdd(&cnt2[fb], 1);
            buf[nb[fb] + k] = (((pk[r] >> 17) & 63) << 17) | (pk[r] & 0x1FFFF);
        }
    }
    __syncthreads();
    for (int fb = 0; fb < FPS; ++fb) {
        int c = cnt[fb], b = gb[fb], o = nb[fb];
        size_t dbase = (size_t)(s * FPS + fb) * CAP + b;
        for (int i = tid; i < c; i += 512)
            if (b + i < CAP) bedges[dbase + i] = buf[o + i];
    }
}

// ---- fused: per-bucket counting sort + layer-1 GAT (4 nodes/wave) + mid GEMM
__global__ __launch_bounds__(512) void k_sortgat1(
        int* __restrict__ bedges, const int* __restrict__ gcur2,
        int* __restrict__ meta,
        const float* __restrict__ xl, const float* __restrict__ xr,
        const float* __restrict__ att, const float* __restrict__ bias,
        const float* __restrict__ Wl2, const float* __restrict__ bl2,
        const float* __restrict__ Wr2, const float* __restrict__ br2,
        float* __restrict__ xl2, float* __restrict__ xr2) {
    __shared__ int sorted[CAP];
    __shared__ int hist[BKT], nbase[BKT], scnt[BKT];
    int bkt = blockIdx.x;
    int tid = threadIdx.x;
    int ecnt = gcur2[bkt]; if (ecnt > CAP) ecnt = CAP;
    int* be = bedges + (size_t)bkt * CAP;
    if (tid < BKT) { hist[tid] = 0; scnt[tid] = 0; }
    __syncthreads();
    int pkc[5];                        // register-cached packed edges
    {
        int r = 0;
        for (int i = tid; i < ecnt; i += 512, ++r) {
            pkc[r] = be[i];
            atomicAdd(&hist[pkc[r] >> 17], 1);
        }
    }
    __syncthreads();
    if (tid < BKT) {                   // wave-parallel exclusive scan
        int v = hist[tid], inc = v;
        #pragma unroll
        for (int off = 1; off < 64; off <<= 1) {
            int u = __shfl_up(inc, off, 64);
            if (tid >= off) inc += u;
        }
        nbase[tid] = inc - v;
        meta[bkt * BKT + tid] = ((inc - v) << 16) | v;   // for layer 2
    }
    __syncthreads();
    {
        int r = 0;
        for (int i = tid; i < ecnt; i += 512, ++r) {
            int pk = pkc[r];
            int dl = pk >> 17;
            int k = atomicAdd(&scnt[dl], 1);
            sorted[nbase[dl] + k] = pk & 0x1FFFF;
        }
    }
    __syncthreads();
    for (int i = tid; i < ecnt; i += 512)   // writeback for layer 2
        be[i] = sorted[i];

    // ---- layer-1 GAT (D=8): 4 nodes per wave, 16 lanes per node ----
    int lane = tid & 63, wave = tid >> 6;
    int grp  = lane >> 4;              // node group 0..3
    int l16  = lane & 15;
    int q    = l16 & 1;                // 16B half of the 8-dim row
    int eo   = l16 >> 1;               // edge slot 0..7 (EPC=8)

    float attq[4], biasq[4];
    #pragma unroll
    for (int j = 0; j < 4; ++j) { attq[j] = att[q * 4 + j]; biasq[j] = bias[q * 4 + j]; }
    float wl2c[H1], wr2c[H1];
    #pragma unroll
    for (int d = 0; d < H1; ++d) {
        wl2c[d] = Wl2[d * C2 + l16];
        wr2c[d] = Wr2[d * C2 + l16];
    }
    float bl2c = bl2[l16], br2c = br2[l16];

    #pragma unroll
    for (int np = 0; np < 2; ++np) {
        int n = np * 32 + wave * 4 + grp;          // 0..63, each exactly once
        int g = bkt * BKT + n;
        int gc = g < NN ? g : NN - 1;
        int deg = hist[n] + 1;                     // + self-loop (e==0)
        int nb_ = nbase[n];

        float4 xr4 = ((const float4*)(xr + (size_t)gc * H1))[q];
        float xrq[4] = {xr4.x, xr4.y, xr4.z, xr4.w};

        float denom = 0.f;
        float acc[4] = {0.f, 0.f, 0.f, 0.f};
        int mc = (deg + 7) >> 3;                   // chunks of 8

        for (int c = 0; c < mc; ++c) {
            int e = c * 8 + eo;
            int src = (e > 0 && e < deg) ? sorted[nb_ + e - 1] : gc;
            float4 v = ((const float4*)(xl + (size_t)src * H1))[q];
            float xa[4] = {v.x, v.y, v.z, v.w};
            float s = 0.f;
            #pragma unroll
            for (int j = 0; j < 4; ++j) {
                float w = xa[j] + xrq[j];
                w = fmaxf(w, NEG * w);             // leaky-relu
                s = fmaf(attq[j], w, s);
            }
            s += __shfl_xor(s, 1, 64);             // combine 2 halves
            float ex = (e < deg) ? __expf(s) : 0.f;
            denom += ex;
            #pragma unroll
            for (int j = 0; j < 4; ++j)
                acc[j] = fmaf(ex, xa[j], acc[j]);
        }

        // reduce over 8 edge slots (xor 2,4,8) -- shared by all 4 nodes
        #pragma unroll
        for (int off = 2; off <= 8; off <<= 1) {
            denom += __shfl_xor(denom, off, 64);
            #pragma unroll
            for (int j = 0; j < 4; ++j)
                acc[j] += __shfl_xor(acc[j], off, 64);
        }
        float inv = 1.f / denom;

        float h[4];
        #pragma unroll
        for (int j = 0; j < 4; ++j)
            h[j] = fmaxf(acc[j] * inv + biasq[j], 0.f);
        // gather this node's h[0..7]: dim d lives at lane grpbase + (d>>2)
        float hd[H1];
        #pragma unroll
        for (int d = 0; d < H1; ++d)
            hd[d] = __shfl(h[d & 3], (lane & 0x30) + (d >> 2), 64);
        // mid GEMM: all 64 lanes active (4 nodes x 16 channels)
        float al = bl2c, ar = br2c;
        #pragma unroll
        for (int d = 0; d < H1; ++d) {
            al = fmaf(hd[d], wl2c[d], al);
            ar = fmaf(hd[d], wr2c[d], ar);
        }
        if (g < NN) {
            xl2[(size_t)g * C2 + l16] = al;
            xr2[(size_t)g * C2 + l16] = ar;
        }
    }
}

// ---- layer-2 GAT gather (D=16): 4 nodes/wave, scalarized meta/addresses ----
__global__ __launch_bounds__(128) void k_gat2L(
        const int* __restrict__ sorted_g, const int* __restrict__ meta,
        const float* __restrict__ xl, const float* __restrict__ xr,
        const float* __restrict__ att, const float* __restrict__ bias,
        float* __restrict__ out) {
    int wv = (blockIdx.x * 128 + threadIdx.x) >> 6;
    int gbase = __builtin_amdgcn_readfirstlane(wv << 2);
    int lane = threadIdx.x & 63;
    int q = lane & 3, eo = lane >> 2;       // LPE=4, EPC=16

    float attq[4], biasq[4];
    #pragma unroll
    for (int j = 0; j < 4; ++j) { attq[j] = att[q * 4 + j]; biasq[j] = bias[q * 4 + j]; }

    #pragma unroll 2
    for (int i = 0; i < 4; ++i) {
        int g = gbase + i;
        int mt = meta[g];                   // s_load (g scalar)
        int deg = (mt & 0xFFFF) + 1;
        const int* sg = sorted_g + (size_t)(g >> 6) * CAP + (mt >> 16);

        float4 xr4 = ((const float4*)(xr + (size_t)g * C2))[q];
        float xrq[4] = {xr4.x, xr4.y, xr4.z, xr4.w};

        float denom = 0.f;
        float acc[4] = {0.f, 0.f, 0.f, 0.f};

        #pragma unroll
        for (int c = 0; c < 4; ++c) {
            if (c == 0 || deg > c * 16) {   // wave-uniform guard
                int e = c * 16 + eo;
                int src = (e > 0 && e < deg) ? sg[e - 1] : g;
                float4 v = ((const float4*)(xl + (size_t)src * C2))[q];
                float xv[4] = {v.x, v.y, v.z, v.w};
                float s = 0.f;
                #pragma unroll
                for (int j = 0; j < 4; ++j) {
                    float w = xv[j] + xrq[j];
                    w = fmaxf(w, NEG * w);
                    s = fmaf(attq[j], w, s);
                }
                s += __shfl_xor(s, 1, 64);
                s += __shfl_xor(s, 2, 64);
                float ex = (e < deg) ? __expf(s) : 0.f;
                denom += ex;
                #pragma unroll
                for (int j = 0; j < 4; ++j)
                    acc[j] = fmaf(ex, xv[j], acc[j]);
            }
        }
        for (int e0 = 64; e0 < deg; e0 += 16) {   // rare: deg > 64
            int e = e0 + eo;
            int src = (e < deg) ? sg[e - 1] : g;
            float4 v = ((const float4*)(xl + (size_t)src * C2))[q];
            float xv[4] = {v.x, v.y, v.z, v.w};
            float s = 0.f;
            #pragma unroll
            for (int j = 0; j < 4; ++j) {
                float w = xv[j] + xrq[j];
                w = fmaxf(w, NEG * w);
                s = fmaf(attq[j], w, s);
            }
            s += __shfl_xor(s, 1, 64);
            s += __shfl_xor(s, 2, 64);
            float ex = (e < deg) ? __expf(s) : 0.f;
            denom += ex;
            #pragma unroll
            for (int j = 0; j < 4; ++j)
                acc[j] = fmaf(ex, xv[j], acc[j]);
        }

        #pragma unroll
        for (int off = 4; off < 64; off <<= 1) {
            denom += __shfl_xor(denom, off, 64);
            #pragma unroll
            for (int j = 0; j < 4; ++j)
                acc[j] += __shfl_xor(acc[j], off, 64);
        }
        float inv = 1.f / denom;

        if (eo == 0) {
            float4 r;
            r.x = acc[0] * inv + biasq[0];
            r.y = acc[1] * inv + biasq[1];
            r.z = acc[2] * inv + biasq[2];
            r.w = acc[3] * inv + biasq[3];
            ((float4*)(out + (size_t)g * C2))[q] = r;
        }
    }
}

extern "C" void kernel_launch(void* const* d_in, const int* in_sizes, int n_in,
                              void* d_out, int out_size, void* d_ws, size_t ws_size,
                              hipStream_t stream) {
    const float* x     = (const float*)d_in[0];
    const int*   ei    = (const int*)d_in[1];
    const float* Wl1   = (const float*)d_in[2];
    const float* bl1   = (const float*)d_in[3];
    const float* Wr1   = (const float*)d_in[4];
    const float* br1   = (const float*)d_in[5];
    const float* att1  = (const float*)d_in[6];
    const float* bias1 = (const float*)d_in[7];
    const float* Wl2   = (const float*)d_in[8];
    const float* bl2   = (const float*)d_in[9];
    const float* Wr2   = (const float*)d_in[10];
    const float* br2   = (const float*)d_in[11];
    const float* att2  = (const float*)d_in[12];
    const float* bias2 = (const float*)d_in[13];
    float* out = (float*)d_out;

    // workspace layout
    int* bedges = (int*)d_ws;                        // NBP*CAP (sorted in-place)
    int* gcur1  = bedges + (size_t)NBP * CAP;        // 32
    int* gcur2  = gcur1 + SB;                        // NBP
    int* meta   = gcur2 + NBP;                       // NBP*64
    float* xl1  = (float*)(meta + NBP * BKT);        // NN*H1
    float* xr1  = xl1 + (size_t)NN * H1;             // NN*H1
    int* sup1   = (int*)(xr1 + (size_t)NN * H1);     // SB*SCAP (14.08 MB)
    float* xl2  = (float*)sup1;                      // overlay: sup1 dead after k_p2
    float* xr2  = xl2 + (size_t)NN * C2;             // NN*C2

    k_clr<<<4, 512, 0, stream>>>(gcur1);
    k_b<<<2605, 512, 0, stream>>>(x, Wl1, bl1, Wr1, br1, xl1, xr1,
                                  ei, gcur1, sup1);
    k_p2<<<1024, 512, 0, stream>>>(sup1, gcur1, gcur2, bedges);
    k_sortgat1<<<NB, 512, 0, stream>>>(bedges, gcur2, meta, xl1, xr1, att1, bias1,
                                       Wl2, bl2, Wr2, br2, xl2, xr2);
    k_gat2L<<<12500, 128, 0, stream>>>(bedges, meta, xl2, xr2, att2, bias2, out);
}

// Round 15
// 124.570 us; speedup vs baseline: 1.3495x; 1.1072x over previous
//
#include <hip/hip_runtime.h>

#define NN 100000
#define NE 3200000
#define FIN 256
#define H1 8
#define C2 16
#define NEG 0.2f

#define BKT 64                        // dst nodes per fine bucket
#define NB 1563                       // fine buckets with real nodes
#define NBP 1568                      // padded fine buckets (32 supers * 49)
#define CAP 2560                      // max edges per fine bucket (mean 2048)
#define SB 32                         // super-buckets
#define SBN 3136                      // nodes per super (49 * 64)
#define FPS 49                        // fine buckets per super
#define SCAP 110000                   // super region capacity (mean 100352)
#define P1B 1024                      // partition-1 logical blocks
#define EPB1 3125                     // NE / P1B
#define LINB 1563                     // lin logical blocks (64 nodes each)
#define P2CAP 3520                    // >= max super slice

// ---- tiny clear kernel ----
__global__ __launch_bounds__(512) void k_clr(int* __restrict__ g) {
    int i = blockIdx.x * 512 + threadIdx.x;
    if (i < SB + NBP) g[i] = 0;
}

// ---- fused front kernel: role by blockIdx%5 (3 lin : 2 p1) ----
__global__ __launch_bounds__(512) void k_b(
        const float* __restrict__ x,
        const float* __restrict__ Wl, const float* __restrict__ bl,
        const float* __restrict__ Wr, const float* __restrict__ br,
        float* __restrict__ xl1, float* __restrict__ xr1,
        const int* __restrict__ ei,
        int* __restrict__ gcur1, int* __restrict__ sup1) {
    __shared__ int smem[10240];        // 40 KB shared by both roles
    int tid = threadIdx.x;
    int m = blockIdx.x % 5, d = blockIdx.x / 5;

    if (m >= 3) {
        // ---------------- partition stage 1 ----------------
        int p1 = d * 2 + (m - 3);
        if (p1 >= P1B) return;
        int* buf  = smem;              // EPB1
        int* cnt  = smem + EPB1;
        int* nb   = cnt + SB;
        int* cnt2 = nb + SB;
        int* gb   = cnt2 + SB;
        int base = p1 * EPB1;
        if (tid < SB) { cnt[tid] = 0; cnt2[tid] = 0; }
        int es[7], ed[7];
        #pragma unroll
        for (int r = 0; r < 7; ++r) {
            int i = tid + r * 512;
            if (i < EPB1) { es[r] = ei[base + i]; ed[r] = ei[NE + base + i]; }
        }
        __syncthreads();
        #pragma unroll
        for (int r = 0; r < 7; ++r) {
            int i = tid + r * 512;
            if (i < EPB1) atomicAdd(&cnt[ed[r] / SBN], 1);
        }
        __syncthreads();
        if (tid < SB) {                // scan + global reserve
            int v = cnt[tid], inc = v;
            #pragma unroll
            for (int off = 1; off < SB; off <<= 1) {
                int u = __shfl_up(inc, off, 64);
                if (tid >= off) inc += u;
            }
            nb[tid] = inc - v;
            gb[tid] = atomicAdd(&gcur1[tid], v);
        }
        __syncthreads();
        #pragma unroll
        for (int r = 0; r < 7; ++r) {
            int i = tid + r * 512;
            if (i < EPB1) {
                int s = ed[r] / SBN;
                int rr = ed[r] - s * SBN;
                int k = atomicAdd(&cnt2[s], 1);
                buf[nb[s] + k] = (rr << 17) | es[r];
            }
        }
        __syncthreads();
        // index-parallel flush: binary search bucket via prefix nb[]
        for (int j = tid; j < EPB1; j += 512) {
            int s = 0;
            #pragma unroll
            for (int st = 16; st >= 1; st >>= 1) {
                int c = s + st;
                if (c < SB && nb[c] <= j) s = c;
            }
            int dst = gb[s] + (j - nb[s]);
            if (dst < SCAP) sup1[(size_t)s * SCAP + dst] = buf[j];
        }
    } else {
        // ---- layer-1 linear: swizzled x tile in LDS, weights via s_load ----
        int lb = d * 3 + m;            // 0..1562
        if (lb >= LINB) return;
        int blkNode = lb * 64;
        float* xf   = (float*)smem;    // [64][128], XOR-swizzled float4 cols
        float* part = (float*)smem;    // reuse: [8][64][20]
        int lane = tid & 63;
        int wq = __builtin_amdgcn_readfirstlane(tid >> 6);   // k-sixteenth 0..7

        float accl[8] = {0,0,0,0,0,0,0,0}, accr[8] = {0,0,0,0,0,0,0,0};

        #pragma unroll
        for (int ph = 0; ph < 2; ++ph) {
            __syncthreads();
            // stage half tile (64 rows x 128 cols), coalesced + swizzled
            #pragma unroll
            for (int pass = 0; pass < 4; ++pass) {
                int i = tid + pass * 512;      // float4 index, 2048 total
                int row = i >> 5, c4 = i & 31;
                int node = blkNode + row; if (node >= NN) node = NN - 1;
                float4 v = *(const float4*)(x + (size_t)node * FIN + ph * 128 + c4 * 4);
                *(float4*)&xf[row * 128 + ((c4 ^ (row & 7)) << 2)] = v;
            }
            __syncthreads();
            int kbase = ph * 128 + wq * 16;
            const float* wlp = Wl + kbase * 8;     // scalar (wave-uniform)
            const float* wrp = Wr + kbase * 8;
            const float* xbase = &xf[lane * 128];
            int lsw = lane & 7;
            #pragma unroll
            for (int jq = 0; jq < 4; ++jq) {
                int f = wq * 4 + jq;
                float4 xv = *(const float4*)(xbase + ((f ^ lsw) << 2));
                float xa[4] = {xv.x, xv.y, xv.z, xv.w};
                #pragma unroll
                for (int r = 0; r < 4; ++r) {
                    int k = jq * 4 + r;
                    #pragma unroll
                    for (int h = 0; h < 8; ++h) {
                        accl[h] = fmaf(xa[r], wlp[k * 8 + h], accl[h]);
                        accr[h] = fmaf(xa[r], wrp[k * 8 + h], accr[h]);
                    }
                }
            }
        }
        __syncthreads();
        float* pw = part + (size_t)(wq * 64 + lane) * 20;
        *(float4*)(pw)      = make_float4(accl[0], accl[1], accl[2], accl[3]);
        *(float4*)(pw + 4)  = make_float4(accl[4], accl[5], accl[6], accl[7]);
        *(float4*)(pw + 8)  = make_float4(accr[0], accr[1], accr[2], accr[3]);
        *(float4*)(pw + 12) = make_float4(accr[4], accr[5], accr[6], accr[7]);
        __syncthreads();
        int n2 = tid >> 3, p = tid & 7;
        float s0 = 0.f, s1 = 0.f;
        #pragma unroll
        for (int w2 = 0; w2 < 8; ++w2) {
            const float* pr = part + (size_t)(w2 * 64 + n2) * 20 + p * 2;
            s0 += pr[0]; s1 += pr[1];
        }
        int node = blkNode + n2;
        if (node < NN) {
            int o = p * 2;
            if (o < 8) {
                s0 += bl[o]; s1 += bl[o + 1];
                *(float2*)(xl1 + (size_t)node * H1 + o) = make_float2(s0, s1);
            } else {
                s0 += br[o - 8]; s1 += br[o - 7];
                *(float2*)(xr1 + (size_t)node * H1 + (o - 8)) = make_float2(s0, s1);
            }
        }
    }
}

// ---- partition stage 2: super slice -> 49 fine buckets (32 slices/super) ---
__global__ __launch_bounds__(512) void k_p2(const int* __restrict__ sup1,
                                            const int* __restrict__ gcur1,
                                            int* __restrict__ gcur2,
                                            int* __restrict__ bedges) {
    __shared__ int buf[P2CAP];
    __shared__ int cnt[FPS], nb[FPS], cnt2[FPS], gb[FPS];
    int s   = blockIdx.x >> 5;
    int sub = blockIdx.x & 31;
    int tid = threadIdx.x;
    int total = gcur1[s]; if (total > SCAP) total = SCAP;
    int beg = (int)((long)total * sub / 32);
    int end = (int)((long)total * (sub + 1) / 32);
    int n = end - beg;
    const int* sp = sup1 + (size_t)s * SCAP + beg;
    if (tid < FPS) { cnt[tid] = 0; cnt2[tid] = 0; }
    int pk[7];
    #pragma unroll
    for (int r = 0; r < 7; ++r) {
        int i = tid + r * 512;
        if (i < n) pk[r] = sp[i];
    }
    __syncthreads();
    #pragma unroll
    for (int r = 0; r < 7; ++r) {
        int i = tid + r * 512;
        if (i < n) atomicAdd(&cnt[(pk[r] >> 17) >> 6], 1);
    }
    __syncthreads();
    if (tid < 64) {
        int v = (tid < FPS) ? cnt[tid] : 0, inc = v;
        #pragma unroll
        for (int off = 1; off < 64; off <<= 1) {
            int u = __shfl_up(inc, off, 64);
            if (tid >= off) inc += u;
        }
        if (tid < FPS) {
            nb[tid] = inc - v;
            gb[tid] = atomicAdd(&gcur2[s * FPS + tid], v);
        }
    }
    __syncthreads();
    #pragma unroll
    for (int r = 0; r < 7; ++r) {
        int i = tid + r * 512;
        if (i < n) {
            int fb = (pk[r] >> 17) >> 6;
            int k = atomicAdd(&cnt2[fb], 1);
            buf[nb[fb] + k] = (((pk[r] >> 17) & 63) << 17) | (pk[r] & 0x1FFFF);
        }
    }
    __syncthreads();
    // index-parallel flush: binary search fine bucket via prefix nb[]
    for (int j = tid; j < n; j += 512) {
        int fb = 0;
        #pragma unroll
        for (int st = 32; st >= 1; st >>= 1) {
            int c = fb + st;
            if (c < FPS && nb[c] <= j) fb = c;
        }
        int dst = gb[fb] + (j - nb[fb]);
        if (dst < CAP) bedges[(size_t)(s * FPS + fb) * CAP + dst] = buf[j];
    }
}

// ---- fused: per-bucket counting sort + layer-1 GAT (4 nodes/wave) + mid GEMM
__global__ __launch_bounds__(512) void k_sortgat1(
        int* __restrict__ bedges, const int* __restrict__ gcur2,
        int* __restrict__ meta,
        const float* __restrict__ xl, const float* __restrict__ xr,
        const float* __restrict__ att, const float* __restrict__ bias,
        const float* __restrict__ Wl2, const float* __restrict__ bl2,
        const float* __restrict__ Wr2, const float* __restrict__ br2,
        float* __restrict__ xl2, float* __restrict__ xr2) {
    __shared__ int sorted[CAP];
    __shared__ int hist[BKT], nbase[BKT], scnt[BKT];
    int bkt = blockIdx.x;
    int tid = threadIdx.x;
    int ecnt = gcur2[bkt]; if (ecnt > CAP) ecnt = CAP;
    int* be = bedges + (size_t)bkt * CAP;
    if (tid < BKT) { hist[tid] = 0; scnt[tid] = 0; }
    __syncthreads();
    int pkc[5];                        // register-cached packed edges
    {
        int r = 0;
        for (int i = tid; i < ecnt; i += 512, ++r) {
            pkc[r] = be[i];
            atomicAdd(&hist[pkc[r] >> 17], 1);
        }
    }
    __syncthreads();
    if (tid < BKT) {                   // wave-parallel exclusive scan
        int v = hist[tid], inc = v;
        #pragma unroll
        for (int off = 1; off < 64; off <<= 1) {
            int u = __shfl_up(inc, off, 64);
            if (tid >= off) inc += u;
        }
        nbase[tid] = inc - v;
        meta[bkt * BKT + tid] = ((inc - v) << 16) | v;   // for layer 2
    }
    __syncthreads();
    {
        int r = 0;
        for (int i = tid; i < ecnt; i += 512, ++r) {
            int pk = pkc[r];
            int dl = pk >> 17;
            int k = atomicAdd(&scnt[dl], 1);
            sorted[nbase[dl] + k] = pk & 0x1FFFF;
        }
    }
    __syncthreads();
    for (int i = tid; i < ecnt; i += 512)   // writeback for layer 2
        be[i] = sorted[i];

    // ---- layer-1 GAT (D=8): 4 nodes per wave, 16 lanes per node ----
    int lane = tid & 63, wave = tid >> 6;
    int grp  = lane >> 4;              // node group 0..3
    int l16  = lane & 15;
    int q    = l16 & 1;                // 16B half of the 8-dim row
    int eo   = l16 >> 1;               // edge slot 0..7 (EPC=8)

    float attq[4], biasq[4];
    #pragma unroll
    for (int j = 0; j < 4; ++j) { attq[j] = att[q * 4 + j]; biasq[j] = bias[q * 4 + j]; }
    float wl2c[H1], wr2c[H1];
    #pragma unroll
    for (int d = 0; d < H1; ++d) {
        wl2c[d] = Wl2[d * C2 + l16];
        wr2c[d] = Wr2[d * C2 + l16];
    }
    float bl2c = bl2[l16], br2c = br2[l16];

    #pragma unroll
    for (int np = 0; np < 2; ++np) {
        int n = np * 32 + wave * 4 + grp;          // 0..63, each exactly once
        int g = bkt * BKT + n;
        int gc = g < NN ? g : NN - 1;
        int deg = hist[n] + 1;                     // + self-loop (e==0)
        int nb_ = nbase[n];

        float4 xr4 = ((const float4*)(xr + (size_t)gc * H1))[q];
        float xrq[4] = {xr4.x, xr4.y, xr4.z, xr4.w};

        float denom = 0.f;
        float acc[4] = {0.f, 0.f, 0.f, 0.f};
        int mc = (deg + 7) >> 3;                   // chunks of 8

        for (int c = 0; c < mc; ++c) {
            int e = c * 8 + eo;
            int src = (e > 0 && e < deg) ? sorted[nb_ + e - 1] : gc;
            float4 v = ((const float4*)(xl + (size_t)src * H1))[q];
            float xa[4] = {v.x, v.y, v.z, v.w};
            float s = 0.f;
            #pragma unroll
            for (int j = 0; j < 4; ++j) {
                float w = xa[j] + xrq[j];
                w = fmaxf(w, NEG * w);             // leaky-relu
                s = fmaf(attq[j], w, s);
            }
            s += __shfl_xor(s, 1, 64);             // combine 2 halves
            float ex = (e < deg) ? __expf(s) : 0.f;
            denom += ex;
            #pragma unroll
            for (int j = 0; j < 4; ++j)
                acc[j] = fmaf(ex, xa[j], acc[j]);
        }

        // reduce over 8 edge slots (xor 2,4,8) -- shared by all 4 nodes
        #pragma unroll
        for (int off = 2; off <= 8; off <<= 1) {
            denom += __shfl_xor(denom, off, 64);
            #pragma unroll
            for (int j = 0; j < 4; ++j)
                acc[j] += __shfl_xor(acc[j], off, 64);
        }
        float inv = 1.f / denom;

        float h[4];
        #pragma unroll
        for (int j = 0; j < 4; ++j)
            h[j] = fmaxf(acc[j] * inv + biasq[j], 0.f);
        // gather this node's h[0..7]: dim d lives at lane grpbase + (d>>2)
        float hd[H1];
        #pragma unroll
        for (int d = 0; d < H1; ++d)
            hd[d] = __shfl(h[d & 3], (lane & 0x30) + (d >> 2), 64);
        // mid GEMM: all 64 lanes active (4 nodes x 16 channels)
        float al = bl2c, ar = br2c;
        #pragma unroll
        for (int d = 0; d < H1; ++d) {
            al = fmaf(hd[d], wl2c[d], al);
            ar = fmaf(hd[d], wr2c[d], ar);
        }
        if (g < NN) {
            xl2[(size_t)g * C2 + l16] = al;
            xr2[(size_t)g * C2 + l16] = ar;
        }
    }
}

// ---- layer-2 GAT gather (D=16): 4 nodes/wave, scalarized meta/addresses ----
__global__ __launch_bounds__(128) void k_gat2L(
        const int* __restrict__ sorted_g, const int* __restrict__ meta,
        const float* __restrict__ xl, const float* __restrict__ xr,
        const float* __restrict__ att, const float* __restrict__ bias,
        float* __restrict__ out) {
    int wv = (blockIdx.x * 128 + threadIdx.x) >> 6;
    int gbase = __builtin_amdgcn_readfirstlane(wv << 2);
    int lane = threadIdx.x & 63;
    int q = lane & 3, eo = lane >> 2;       // LPE=4, EPC=16

    float attq[4], biasq[4];
    #pragma unroll
    for (int j = 0; j < 4; ++j) { attq[j] = att[q * 4 + j]; biasq[j] = bias[q * 4 + j]; }

    #pragma unroll 2
    for (int i = 0; i < 4; ++i) {
        int g = gbase + i;
        int mt = meta[g];                   // s_load (g scalar)
        int deg = (mt & 0xFFFF) + 1;
        const int* sg = sorted_g + (size_t)(g >> 6) * CAP + (mt >> 16);

        float4 xr4 = ((const float4*)(xr + (size_t)g * C2))[q];
        float xrq[4] = {xr4.x, xr4.y, xr4.z, xr4.w};

        float denom = 0.f;
        float acc[4] = {0.f, 0.f, 0.f, 0.f};

        #pragma unroll
        for (int c = 0; c < 4; ++c) {
            if (c == 0 || deg > c * 16) {   // wave-uniform guard
                int e = c * 16 + eo;
                int src = (e > 0 && e < deg) ? sg[e - 1] : g;
                float4 v = ((const float4*)(xl + (size_t)src * C2))[q];
                float xv[4] = {v.x, v.y, v.z, v.w};
                float s = 0.f;
                #pragma unroll
                for (int j = 0; j < 4; ++j) {
                    float w = xv[j] + xrq[j];
                    w = fmaxf(w, NEG * w);
                    s = fmaf(attq[j], w, s);
                }
                s += __shfl_xor(s, 1, 64);
                s += __shfl_xor(s, 2, 64);
                float ex = (e < deg) ? __expf(s) : 0.f;
                denom += ex;
                #pragma unroll
                for (int j = 0; j < 4; ++j)
                    acc[j] = fmaf(ex, xv[j], acc[j]);
            }
        }
        for (int e0 = 64; e0 < deg; e0 += 16) {   // rare: deg > 64
            int e = e0 + eo;
            int src = (e < deg) ? sg[e - 1] : g;
            float4 v = ((const float4*)(xl + (size_t)src * C2))[q];
            float xv[4] = {v.x, v.y, v.z, v.w};
            float s = 0.f;
            #pragma unroll
            for (int j = 0; j < 4; ++j) {
                float w = xv[j] + xrq[j];
                w = fmaxf(w, NEG * w);
                s = fmaf(attq[j], w, s);
            }
            s += __shfl_xor(s, 1, 64);
            s += __shfl_xor(s, 2, 64);
            float ex = (e < deg) ? __expf(s) : 0.f;
            denom += ex;
            #pragma unroll
            for (int j = 0; j < 4; ++j)
                acc[j] = fmaf(ex, xv[j], acc[j]);
        }

        #pragma unroll
        for (int off = 4; off < 64; off <<= 1) {
            denom += __shfl_xor(denom, off, 64);
            #pragma unroll
            for (int j = 0; j < 4; ++j)
                acc[j] += __shfl_xor(acc[j], off, 64);
        }
        float inv = 1.f / denom;

        if (eo == 0) {
            float4 r;
            r.x = acc[0] * inv + biasq[0];
            r.y = acc[1] * inv + biasq[1];
            r.z = acc[2] * inv + biasq[2];
            r.w = acc[3] * inv + biasq[3];
            ((float4*)(out + (size_t)g * C2))[q] = r;
        }
    }
}

extern "C" void kernel_launch(void* const* d_in, const int* in_sizes, int n_in,
                              void* d_out, int out_size, void* d_ws, size_t ws_size,
                              hipStream_t stream) {
    const float* x     = (const float*)d_in[0];
    const int*   ei    = (const int*)d_in[1];
    const float* Wl1   = (const float*)d_in[2];
    const float* bl1   = (const float*)d_in[3];
    const float* Wr1   = (const float*)d_in[4];
    const float* br1   = (const float*)d_in[5];
    const float* att1  = (const float*)d_in[6];
    const float* bias1 = (const float*)d_in[7];
    const float* Wl2   = (const float*)d_in[8];
    const float* bl2   = (const float*)d_in[9];
    const float* Wr2   = (const float*)d_in[10];
    const float* br2   = (const float*)d_in[11];
    const float* att2  = (const float*)d_in[12];
    const float* bias2 = (const float*)d_in[13];
    float* out = (float*)d_out;

    // workspace layout
    int* bedges = (int*)d_ws;                        // NBP*CAP (sorted in-place)
    int* gcur1  = bedges + (size_t)NBP * CAP;        // 32
    int* gcur2  = gcur1 + SB;                        // NBP
    int* meta   = gcur2 + NBP;                       // NBP*64
    float* xl1  = (float*)(meta + NBP * BKT);        // NN*H1
    float* xr1  = xl1 + (size_t)NN * H1;             // NN*H1
    int* sup1   = (int*)(xr1 + (size_t)NN * H1);     // SB*SCAP (14.08 MB)
    float* xl2  = (float*)sup1;                      // overlay: sup1 dead after k_p2
    float* xr2  = xl2 + (size_t)NN * C2;             // NN*C2

    k_clr<<<4, 512, 0, stream>>>(gcur1);
    k_b<<<2605, 512, 0, stream>>>(x, Wl1, bl1, Wr1, br1, xl1, xr1,
                                  ei, gcur1, sup1);
    k_p2<<<1024, 512, 0, stream>>>(sup1, gcur1, gcur2, bedges);
    k_sortgat1<<<NB, 512, 0, stream>>>(bedges, gcur2, meta, xl1, xr1, att1, bias1,
                                       Wl2, bl2, Wr2, br2, xl2, xr2);
    k_gat2L<<<12500, 128, 0, stream>>>(bedges, meta, xl2, xr2, att2, bias2, out);
}